// Round 4
// baseline (388.970 us; speedup 1.0000x reference)
//
#include <hip/hip_runtime.h>

typedef __bf16 bf16;
typedef __bf16 bf16x8 __attribute__((ext_vector_type(8)));
typedef float floatx4 __attribute__((ext_vector_type(4)));

#define IN_F  1024
#define OUT_F 4096
#define M_DIM 8192   // 16*512
#define K_DIM 1024
#define N_DIM 4096

__device__ __forceinline__ unsigned short f2bf(float f) {
    unsigned int u = __float_as_uint(f);
    u += 0x7FFFu + ((u >> 16) & 1u);   // round-to-nearest-even
    return (unsigned short)(u >> 16);
}

// ---------------------------------------------------------------------------
// Kernel 1 (FUSED prep): blocks [0,1024) build W' (factored diagonal sums),
// blocks [1024,5120) convert x f32->bf16. One launch instead of two serial
// launches (independent work; whole blocks take one branch -> no divergence).
// ---------------------------------------------------------------------------
__global__ __launch_bounds__(256) void prep_kernel(
    const float* __restrict__ W, const float* __restrict__ alphas,
    const float* __restrict__ x,
    unsigned short* __restrict__ Wb, uint4* __restrict__ xb)
{
    const int t = threadIdx.x;

    if (blockIdx.x >= 1024) {
        // ---- cvt_x part: 8 f32 -> 8 bf16 per thread ----
        const int g = (blockIdx.x - 1024) * 256 + t;
        const float4* xv = (const float4*)x;
        const float4 v0 = xv[2 * g];
        const float4 v1 = xv[2 * g + 1];
        uint4 o;
        o.x = (unsigned)f2bf(v0.x) | ((unsigned)f2bf(v0.y) << 16);
        o.y = (unsigned)f2bf(v0.z) | ((unsigned)f2bf(v0.w) << 16);
        o.z = (unsigned)f2bf(v1.x) | ((unsigned)f2bf(v1.y) << 16);
        o.w = (unsigned)f2bf(v1.z) | ((unsigned)f2bf(v1.w) << 16);
        xb[g] = o;
        return;
    }

    // ---- build_w part ----
    __shared__ __align__(16) float Wl[16 * 256];   // 16 KB source strip
    __shared__ __align__(16) float D2[2048];       // 8 KB
    __shared__ float D4[1024];                     // 4 KB
    __shared__ float D8[512];                      // 2 KB
    __shared__ float D16[256];                     // 1 KB

    const int rb = blockIdx.x >> 2;      // 256 row-blocks of 16 rows
    const int cb = blockIdx.x & 3;       // 4 col-blocks of 256 cols
    const int row0 = rb * 16, col0 = cb * 256;

    // pass 1: load strip (float4, coalesced)
    const float4* src = (const float4*)(W + (size_t)row0 * IN_F + col0);
    #pragma unroll
    for (int j = 0; j < 4; ++j) {
        const int idx = j * 256 + t;
        const int r = idx >> 6, c4 = idx & 63;
        ((float4*)Wl)[r * 64 + c4] = src[(size_t)r * 256 + c4];
    }

    // softmax over 5 alphas; fold in 1/bs
    float av[5];
    float mx = -1e30f;
    #pragma unroll
    for (int j = 0; j < 5; ++j) { av[j] = alphas[j]; mx = fmaxf(mx, av[j]); }
    float s = 0.f;
    #pragma unroll
    for (int j = 0; j < 5; ++j) { av[j] = __expf(av[j] - mx); s += av[j]; }
    const float inv = 1.f / s;
    #pragma unroll
    for (int j = 0; j < 5; ++j) av[j] *= inv;
    #pragma unroll
    for (int e = 1; e <= 4; ++e) av[e] *= 1.0f / (float)(1 << e);

    __syncthreads();

    // pass 2: per-(block,level,diagonal) sums, each computed once
    {   const int c16 = t >> 4, d = t & 15;
        float acc = 0.f;
        #pragma unroll
        for (int r = 0; r < 16; ++r)
            acc += Wl[r * 256 + c16 * 16 + ((r + d) & 15)];
        D16[t] = acc;
    }
    #pragma unroll
    for (int it = 0; it < 2; ++it) {
        const int s8 = t + it * 256;
        const int d = s8 & 7, c8 = (s8 >> 3) & 31, r8 = s8 >> 8;
        float acc = 0.f;
        #pragma unroll
        for (int r = 0; r < 8; ++r)
            acc += Wl[(r8 * 8 + r) * 256 + c8 * 8 + ((r + d) & 7)];
        D8[s8] = acc;
    }
    #pragma unroll
    for (int it = 0; it < 4; ++it) {
        const int s4 = t + it * 256;
        const int d = s4 & 3, c4 = (s4 >> 2) & 63, r4 = s4 >> 8;
        float acc = 0.f;
        #pragma unroll
        for (int r = 0; r < 4; ++r)
            acc += Wl[(r4 * 4 + r) * 256 + c4 * 4 + ((r + d) & 3)];
        D4[s4] = acc;
    }
    #pragma unroll
    for (int it = 0; it < 8; ++it) {
        const int s2 = t + it * 256;
        const int d = s2 & 1, c2 = (s2 >> 1) & 127, r2 = s2 >> 8;
        D2[s2] = Wl[(r2 * 2) * 256 + c2 * 2 + d]
               + Wl[(r2 * 2 + 1) * 256 + c2 * 2 + ((1 + d) & 1)];
    }

    __syncthreads();

    // pass 3: 16 outputs/thread, 5 LDS lookups each
    const int k = t >> 4, jj = t & 15;
    float res[16];
    #pragma unroll
    for (int jb = 0; jb < 16; ++jb) {
        const int col = jb * 16 + jj;
        const int dd = k - col;
        res[jb] = av[0] * Wl[k * 256 + col]
                + av[1] * D2[((k >> 1) * 128 + (col >> 1)) * 2 + (dd & 1)]
                + av[2] * D4[((k >> 2) * 64  + (col >> 2)) * 4 + (dd & 3)]
                + av[3] * D8[((k >> 3) * 32  + (col >> 3)) * 8 + (dd & 7)]
                + av[4] * D16[(col >> 4) * 16 + (dd & 15)];
    }

    // repack through LDS (reuse D2 region) for uint4 stores
    __syncthreads();
    unsigned short* st = (unsigned short*)D2;
    #pragma unroll
    for (int jb = 0; jb < 16; ++jb)
        st[k * 256 + jb * 16 + jj] = f2bf(res[jb]);
    __syncthreads();

    const uint4* p = (const uint4*)(st + k * 256 + jj * 16);
    uint4* dst = (uint4*)(Wb + (size_t)(row0 + k) * IN_F + col0 + jj * 16);
    dst[0] = p[0];
    dst[1] = p[1];
}

// ---------------------------------------------------------------------------
// Kernel 2 (RESTRUCTURED v4): C = A[M][K] * B[N][K]^T + bias
// TLP-first design (round-3 lesson: 1-block/CU mega-tile serializes the
// 128 MB C-write behind the K-loop; that alone is ~21 us):
//   TM=256 x TN=128, BK=32, 256 threads = 4 waves (2M x 2N), per-wave
//   128x64 output (acc[8][4], flop/LDS-byte = 42.7).
//   LDS: double-buffer 2 x (A 16KB + B 8KB) = 48 KB -> 3 blocks/CU
//   (__launch_bounds__(256,3)), 3 waves/SIMD: one block's epilogue stores and
//   vmcnt stalls hide under the other blocks' MFMA (m114 co-schedule).
//   Counted vmcnt dbuf (T4): stage(t+1) ISSUED first, then vmcnt(6) retires
//   exactly stage(t)'s 6 loads; never a mid-loop drain (only tail t=31).
//   2 barriers/tile. setprio(1) around MFMA cluster (T5).
// Swizzle (0-conflict, verified r2/r3): row = 64 B = 4 chunks of 16 B;
// chunk s of row r holds K-quad s ^ ((r>>1)&3); fragment read uses
// quad ^ ((l16>>1)&3) -> each bank-quad gets exactly 2 lanes (free, m136).
// Staging pre-swizzles the GLOBAL source; LDS dest stays lane-linear
// (global_load_lds requirement).
// ---------------------------------------------------------------------------
#define GTM 256
#define GTN 128
#define GTK 32
#define A_EL (GTM * GTK)          // 8192 el = 16 KB
#define B_EL (GTN * GTK)          // 4096 el =  8 KB
#define BUF_EL (A_EL + B_EL)      // 24 KB per slot

__global__ __launch_bounds__(256, 3) void gemm_bt_kernel(
    const bf16* __restrict__ A, const bf16* __restrict__ B,
    const float* __restrict__ bias, float* __restrict__ C)
{
    constexpr int N = N_DIM, K = K_DIM;
    constexpr int NT = K / GTK;            // 32 K-tiles

    __shared__ __align__(16) bf16 smem[2 * BUF_EL];   // 48 KB

    const int t    = threadIdx.x;
    const int w    = t >> 6;               // wave 0..3
    const int l    = t & 63;
    const int quad = l >> 4;
    const int l16  = l & 15;

    const int wm = (w >> 1) * 128;         // 0,128
    const int wn = (w & 1) * 64;           // 0,64

    const int nb = N / GTN;                // 32
    const int bm = blockIdx.x / nb;
    const int bn = blockIdx.x % nb;
    // natural order: per XCD bn in {x, x+8, x+16, x+24} -> B-panels (4x256KB)
    // resident in its private L2 across all bm (round-1 lesson).

    // fragment read offset within a [rows][32] buffer (elements)
    const int fko = l16 * GTK + ((quad ^ ((l16 >> 1) & 3)) * 8);

    // staging: chunk c (16B) -> row = c>>2, K-quad = (c&3) ^ ((row>>1)&3)
    // A: chunks q*256+t, q=0..3; B: q=0..1.  LDS dest lane-linear.
    const bf16* Ag[4]; int la[4];
    const bf16* Bg[2]; int lb[2];
    {
        const bf16* Abase = A + (size_t)bm * GTM * K;
        const bf16* Bbase = B + (size_t)bn * GTN * K;
        #pragma unroll
        for (int q = 0; q < 4; ++q) {
            const int c = q * 256 + t;
            const int row = c >> 2;
            const int kq = (c & 3) ^ ((row >> 1) & 3);
            Ag[q] = Abase + (size_t)row * K + kq * 8;
            la[q] = (q * 256 + (t & ~63)) * 8;
        }
        #pragma unroll
        for (int q = 0; q < 2; ++q) {
            const int c = q * 256 + t;
            const int row = c >> 2;
            const int kq = (c & 3) ^ ((row >> 1) & 3);
            Bg[q] = Bbase + (size_t)row * K + kq * 8;
            lb[q] = (q * 256 + (t & ~63)) * 8;
        }
    }

    floatx4 acc[8][4] = {};

#define GLL(SRC, DST)                                                         \
    __builtin_amdgcn_global_load_lds(                                         \
        (const __attribute__((address_space(1))) void*)(SRC),                 \
        (__attribute__((address_space(3))) void*)(DST), 16, 0, 0)

#define STAGE(KOFF, BUFP) do {                                                \
        _Pragma("unroll")                                                     \
        for (int q = 0; q < 4; ++q) GLL(Ag[q] + (KOFF), (BUFP) + la[q]);      \
        _Pragma("unroll")                                                     \
        for (int q = 0; q < 2; ++q) GLL(Bg[q] + (KOFF), (BUFP) + A_EL + lb[q]); \
    } while (0)

#define MF(d, va, vb)                                                         \
    d = __builtin_amdgcn_mfma_f32_16x16x32_bf16(va, vb, d, 0, 0, 0)

    // prologue: stage tile 0 -> buf0
    STAGE(0, smem);

    #pragma unroll 1
    for (int kt = 0; kt < NT; ++kt) {
        bf16* cur = smem + (kt & 1) * BUF_EL;
        bf16* nxt = smem + ((kt & 1) ^ 1) * BUF_EL;

        if (kt < NT - 1) {
            STAGE((kt + 1) * GTK, nxt);                      // issue first
            asm volatile("s_waitcnt vmcnt(6)" ::: "memory"); // retire stage(kt)
        } else {
            asm volatile("s_waitcnt vmcnt(0)" ::: "memory"); // tail drain
        }
        __builtin_amdgcn_s_barrier();

        bf16x8 af[8], bfr[4];
        const bf16* a0 = cur + wm * GTK + fko;
        const bf16* b0 = cur + A_EL + wn * GTK + fko;
        #pragma unroll
        for (int n = 0; n < 4; ++n)
            bfr[n] = *(const bf16x8*)(b0 + n * 16 * GTK);
        #pragma unroll
        for (int m = 0; m < 8; ++m)
            af[m] = *(const bf16x8*)(a0 + m * 16 * GTK);

        __builtin_amdgcn_s_setprio(1);
        #pragma unroll
        for (int m = 0; m < 8; ++m)
            #pragma unroll
            for (int n = 0; n < 4; ++n)
                MF(acc[m][n], af[m], bfr[n]);
        __builtin_amdgcn_s_setprio(0);

        __builtin_amdgcn_s_barrier();   // reads(cur) done before next STAGE hits it
    }
#undef STAGE
#undef GLL
#undef MF

    // epilogue: C/D layout col = lane&15, row = quad*4 + reg (m89-verified)
    float bv[4];
    #pragma unroll
    for (int nt = 0; nt < 4; ++nt)
        bv[nt] = bias[bn * GTN + wn + nt * 16 + l16];

    float* Cbase = C + (size_t)(bm * GTM + wm) * N + bn * GTN + wn;
    #pragma unroll
    for (int m = 0; m < 8; ++m) {
        #pragma unroll
        for (int r = 0; r < 4; ++r) {
            float* crowp = Cbase + (size_t)(m * 16 + quad * 4 + r) * N;
            #pragma unroll
            for (int nt = 0; nt < 4; ++nt)
                crowp[nt * 16 + l16] = acc[m][nt][r] + bv[nt];
        }
    }
}

// ---------------------------------------------------------------------------
extern "C" void kernel_launch(void* const* d_in, const int* in_sizes, int n_in,
                              void* d_out, int out_size, void* d_ws, size_t ws_size,
                              hipStream_t stream) {
    const float* x      = (const float*)d_in[0];   // [16,512,1024]
    const float* weight = (const float*)d_in[1];   // [4096,1024]
    const float* alphas = (const float*)d_in[2];   // [5]
    const float* bias   = (const float*)d_in[3];   // [4096]
    float* out = (float*)d_out;                    // [16,512,4096] f32

    // workspace: Wb (bf16, 8 MB) | Xb (bf16, 16 MB)
    unsigned short* Wb = (unsigned short*)d_ws;
    unsigned short* Xb = (unsigned short*)((char*)d_ws + (size_t)OUT_F * IN_F * 2);

    // fused prep: 1024 build_w blocks + 4096 cvt blocks
    prep_kernel<<<1024 + 4096, 256, 0, stream>>>(weight, alphas, x, Wb, (uint4*)Xb);

    const int grid = (M_DIM / GTM) * (N_DIM / GTN);   // 32*32 = 1024 blocks
    gemm_bt_kernel<<<grid, 256, 0, stream>>>((const bf16*)Xb, (const bf16*)Wb, bias, out);
}

// Round 6
// 378.367 us; speedup vs baseline: 1.0280x; 1.0280x over previous
//
#include <hip/hip_runtime.h>

typedef __bf16 bf16;
typedef __bf16 bf16x8 __attribute__((ext_vector_type(8)));
typedef float floatx4 __attribute__((ext_vector_type(4)));

#define IN_F  1024
#define OUT_F 4096
#define M_DIM 8192   // 16*512
#define K_DIM 1024
#define N_DIM 4096

__device__ __forceinline__ unsigned short f2bf(float f) {
    unsigned int u = __float_as_uint(f);
    u += 0x7FFFu + ((u >> 16) & 1u);   // round-to-nearest-even
    return (unsigned short)(u >> 16);
}

// ---------------------------------------------------------------------------
// Kernel 1 (FUSED prep): blocks [0,1024) build W' (factored diagonal sums),
// blocks [1024,5120) convert x f32->bf16. (Fusion cut the non-GEMM gap
// 151 -> 114 us in round 4 -- keep.)
// ---------------------------------------------------------------------------
__global__ __launch_bounds__(256) void prep_kernel(
    const float* __restrict__ W, const float* __restrict__ alphas,
    const float* __restrict__ x,
    unsigned short* __restrict__ Wb, uint4* __restrict__ xb)
{
    const int t = threadIdx.x;

    if (blockIdx.x >= 1024) {
        // ---- cvt_x part: 8 f32 -> 8 bf16 per thread ----
        const int g = (blockIdx.x - 1024) * 256 + t;
        const float4* xv = (const float4*)x;
        const float4 v0 = xv[2 * g];
        const float4 v1 = xv[2 * g + 1];
        uint4 o;
        o.x = (unsigned)f2bf(v0.x) | ((unsigned)f2bf(v0.y) << 16);
        o.y = (unsigned)f2bf(v0.z) | ((unsigned)f2bf(v0.w) << 16);
        o.z = (unsigned)f2bf(v1.x) | ((unsigned)f2bf(v1.y) << 16);
        o.w = (unsigned)f2bf(v1.z) | ((unsigned)f2bf(v1.w) << 16);
        xb[g] = o;
        return;
    }

    // ---- build_w part ----
    __shared__ __align__(16) float Wl[16 * 256];   // 16 KB source strip
    __shared__ __align__(16) float D2[2048];       // 8 KB
    __shared__ float D4[1024];                     // 4 KB
    __shared__ float D8[512];                      // 2 KB
    __shared__ float D16[256];                     // 1 KB

    const int rb = blockIdx.x >> 2;      // 256 row-blocks of 16 rows
    const int cb = blockIdx.x & 3;       // 4 col-blocks of 256 cols
    const int row0 = rb * 16, col0 = cb * 256;

    // pass 1: load strip (float4, coalesced)
    const float4* src = (const float4*)(W + (size_t)row0 * IN_F + col0);
    #pragma unroll
    for (int j = 0; j < 4; ++j) {
        const int idx = j * 256 + t;
        const int r = idx >> 6, c4 = idx & 63;
        ((float4*)Wl)[r * 64 + c4] = src[(size_t)r * 256 + c4];
    }

    // softmax over 5 alphas; fold in 1/bs
    float av[5];
    float mx = -1e30f;
    #pragma unroll
    for (int j = 0; j < 5; ++j) { av[j] = alphas[j]; mx = fmaxf(mx, av[j]); }
    float s = 0.f;
    #pragma unroll
    for (int j = 0; j < 5; ++j) { av[j] = __expf(av[j] - mx); s += av[j]; }
    const float inv = 1.f / s;
    #pragma unroll
    for (int j = 0; j < 5; ++j) av[j] *= inv;
    #pragma unroll
    for (int e = 1; e <= 4; ++e) av[e] *= 1.0f / (float)(1 << e);

    __syncthreads();

    // pass 2: per-(block,level,diagonal) sums, each computed once
    {   const int c16 = t >> 4, d = t & 15;
        float acc = 0.f;
        #pragma unroll
        for (int r = 0; r < 16; ++r)
            acc += Wl[r * 256 + c16 * 16 + ((r + d) & 15)];
        D16[t] = acc;
    }
    #pragma unroll
    for (int it = 0; it < 2; ++it) {
        const int s8 = t + it * 256;
        const int d = s8 & 7, c8 = (s8 >> 3) & 31, r8 = s8 >> 8;
        float acc = 0.f;
        #pragma unroll
        for (int r = 0; r < 8; ++r)
            acc += Wl[(r8 * 8 + r) * 256 + c8 * 8 + ((r + d) & 7)];
        D8[s8] = acc;
    }
    #pragma unroll
    for (int it = 0; it < 4; ++it) {
        const int s4 = t + it * 256;
        const int d = s4 & 3, c4 = (s4 >> 2) & 63, r4 = s4 >> 8;
        float acc = 0.f;
        #pragma unroll
        for (int r = 0; r < 4; ++r)
            acc += Wl[(r4 * 4 + r) * 256 + c4 * 4 + ((r + d) & 3)];
        D4[s4] = acc;
    }
    #pragma unroll
    for (int it = 0; it < 8; ++it) {
        const int s2 = t + it * 256;
        const int d = s2 & 1, c2 = (s2 >> 1) & 127, r2 = s2 >> 8;
        D2[s2] = Wl[(r2 * 2) * 256 + c2 * 2 + d]
               + Wl[(r2 * 2 + 1) * 256 + c2 * 2 + ((1 + d) & 1)];
    }

    __syncthreads();

    // pass 3: 16 outputs/thread, 5 LDS lookups each
    const int k = t >> 4, jj = t & 15;
    float res[16];
    #pragma unroll
    for (int jb = 0; jb < 16; ++jb) {
        const int col = jb * 16 + jj;
        const int dd = k - col;
        res[jb] = av[0] * Wl[k * 256 + col]
                + av[1] * D2[((k >> 1) * 128 + (col >> 1)) * 2 + (dd & 1)]
                + av[2] * D4[((k >> 2) * 64  + (col >> 2)) * 4 + (dd & 3)]
                + av[3] * D8[((k >> 3) * 32  + (col >> 3)) * 8 + (dd & 7)]
                + av[4] * D16[(col >> 4) * 16 + (dd & 15)];
    }

    // repack through LDS (reuse D2 region) for uint4 stores
    __syncthreads();
    unsigned short* st = (unsigned short*)D2;
    #pragma unroll
    for (int jb = 0; jb < 16; ++jb)
        st[k * 256 + jb * 16 + jj] = f2bf(res[jb]);
    __syncthreads();

    const uint4* p = (const uint4*)(st + k * 256 + jj * 16);
    uint4* dst = (uint4*)(Wb + (size_t)(row0 + k) * IN_F + col0 + jj * 16);
    dst[0] = p[0];
    dst[1] = p[1];
}

// ---------------------------------------------------------------------------
// Kernel 2 (v5 = v4 + NONTEMPORAL C stores): C = A[M][K] * B[N][K]^T + bias
// Round-4 lesson: overlapping epilogues with other blocks' K-loop fetch
// streams caused 3.3x HBM write amplification (partially-dirty write-
// allocated C lines evicted between the two 64B stores that fill each 128B
// line, + refetch-for-merge). Fix: nt stores bypass L2 allocation -- each
// 64B quarter-wave segment is a full HBM sector write, written exactly once,
// and C traffic stops evicting the L3-resident A/B panels.
//   TM=256 x TN=128, BK=32, 256 thr = 4 waves (2M x 2N), acc[8][4]/wave.
//   dbuf 48 KB -> 3 blocks/CU; counted vmcnt(6) (stage issued BEFORE wait,
//   never a mid-loop drain); setprio(1) around MFMA cluster.
// Swizzle (0-conflict, verified): chunk s of row r holds K-quad s^((r>>1)&3);
// frag read uses quad^((l16>>1)&3); staging pre-swizzles the GLOBAL source.
// ---------------------------------------------------------------------------
#define GTM 256
#define GTN 128
#define GTK 32
#define A_EL (GTM * GTK)          // 8192 el = 16 KB
#define B_EL (GTN * GTK)          // 4096 el =  8 KB
#define BUF_EL (A_EL + B_EL)      // 24 KB per slot

__global__ __launch_bounds__(256, 3) void gemm_bt_kernel(
    const bf16* __restrict__ A, const bf16* __restrict__ B,
    const float* __restrict__ bias, float* __restrict__ C)
{
    constexpr int N = N_DIM, K = K_DIM;
    constexpr int NT = K / GTK;            // 32 K-tiles

    __shared__ __align__(16) bf16 smem[2 * BUF_EL];   // 48 KB

    const int t    = threadIdx.x;
    const int w    = t >> 6;               // wave 0..3
    const int l    = t & 63;
    const int quad = l >> 4;
    const int l16  = l & 15;

    const int wm = (w >> 1) * 128;         // 0,128
    const int wn = (w & 1) * 64;           // 0,64

    const int nb = N / GTN;                // 32
    const int bm = blockIdx.x / nb;
    const int bn = blockIdx.x % nb;
    // natural order: per XCD bn in {x, x+8, x+16, x+24} -> B-panels resident
    // in its private L2 across all bm (round-1 lesson).

    // fragment read offset within a [rows][32] buffer (elements)
    const int fko = l16 * GTK + ((quad ^ ((l16 >> 1) & 3)) * 8);

    // staging: chunk c (16B) -> row = c>>2, K-quad = (c&3) ^ ((row>>1)&3)
    const bf16* Ag[4]; int la[4];
    const bf16* Bg[2]; int lb[2];
    {
        const bf16* Abase = A + (size_t)bm * GTM * K;
        const bf16* Bbase = B + (size_t)bn * GTN * K;
        #pragma unroll
        for (int q = 0; q < 4; ++q) {
            const int c = q * 256 + t;
            const int row = c >> 2;
            const int kq = (c & 3) ^ ((row >> 1) & 3);
            Ag[q] = Abase + (size_t)row * K + kq * 8;
            la[q] = (q * 256 + (t & ~63)) * 8;
        }
        #pragma unroll
        for (int q = 0; q < 2; ++q) {
            const int c = q * 256 + t;
            const int row = c >> 2;
            const int kq = (c & 3) ^ ((row >> 1) & 3);
            Bg[q] = Bbase + (size_t)row * K + kq * 8;
            lb[q] = (q * 256 + (t & ~63)) * 8;
        }
    }

    floatx4 acc[8][4] = {};

#define GLL(SRC, DST)                                                         \
    __builtin_amdgcn_global_load_lds(                                         \
        (const __attribute__((address_space(1))) void*)(SRC),                 \
        (__attribute__((address_space(3))) void*)(DST), 16, 0, 0)

#define STAGE(KOFF, BUFP) do {                                                \
        _Pragma("unroll")                                                     \
        for (int q = 0; q < 4; ++q) GLL(Ag[q] + (KOFF), (BUFP) + la[q]);      \
        _Pragma("unroll")                                                     \
        for (int q = 0; q < 2; ++q) GLL(Bg[q] + (KOFF), (BUFP) + A_EL + lb[q]); \
    } while (0)

#define MF(d, va, vb)                                                         \
    d = __builtin_amdgcn_mfma_f32_16x16x32_bf16(va, vb, d, 0, 0, 0)

    // prologue: stage tile 0 -> buf0
    STAGE(0, smem);

    #pragma unroll 1
    for (int kt = 0; kt < NT; ++kt) {
        bf16* cur = smem + (kt & 1) * BUF_EL;
        bf16* nxt = smem + ((kt & 1) ^ 1) * BUF_EL;

        if (kt < NT - 1) {
            STAGE((kt + 1) * GTK, nxt);                      // issue first
            asm volatile("s_waitcnt vmcnt(6)" ::: "memory"); // retire stage(kt)
        } else {
            asm volatile("s_waitcnt vmcnt(0)" ::: "memory"); // tail drain
        }
        __builtin_amdgcn_s_barrier();

        bf16x8 af[8], bfr[4];
        const bf16* a0 = cur + wm * GTK + fko;
        const bf16* b0 = cur + A_EL + wn * GTK + fko;
        #pragma unroll
        for (int n = 0; n < 4; ++n)
            bfr[n] = *(const bf16x8*)(b0 + n * 16 * GTK);
        #pragma unroll
        for (int m = 0; m < 8; ++m)
            af[m] = *(const bf16x8*)(a0 + m * 16 * GTK);

        __builtin_amdgcn_s_setprio(1);
        #pragma unroll
        for (int m = 0; m < 8; ++m)
            #pragma unroll
            for (int n = 0; n < 4; ++n)
                MF(acc[m][n], af[m], bfr[n]);
        __builtin_amdgcn_s_setprio(0);

        __builtin_amdgcn_s_barrier();   // reads(cur) done before next STAGE hits it
    }
#undef STAGE
#undef GLL
#undef MF

    // epilogue: C/D layout col = lane&15, row = quad*4 + reg (m89-verified)
    // NONTEMPORAL stores: no L2 write-allocate -> no partial-line evict/merge
    // amplification, no refetch, no A/B eviction from L3.
    float bv[4];
    #pragma unroll
    for (int nt = 0; nt < 4; ++nt)
        bv[nt] = bias[bn * GTN + wn + nt * 16 + l16];

    float* Cbase = C + (size_t)(bm * GTM + wm) * N + bn * GTN + wn;
    #pragma unroll
    for (int m = 0; m < 8; ++m) {
        #pragma unroll
        for (int r = 0; r < 4; ++r) {
            float* crowp = Cbase + (size_t)(m * 16 + quad * 4 + r) * N;
            #pragma unroll
            for (int nt = 0; nt < 4; ++nt)
                __builtin_nontemporal_store(acc[m][nt][r] + bv[nt],
                                            crowp + nt * 16 + l16);
        }
    }
}

// ---------------------------------------------------------------------------
extern "C" void kernel_launch(void* const* d_in, const int* in_sizes, int n_in,
                              void* d_out, int out_size, void* d_ws, size_t ws_size,
                              hipStream_t stream) {
    const float* x      = (const float*)d_in[0];   // [16,512,1024]
    const float* weight = (const float*)d_in[1];   // [4096,1024]
    const float* alphas = (const float*)d_in[2];   // [5]
    const float* bias   = (const float*)d_in[3];   // [4096]
    float* out = (float*)d_out;                    // [16,512,4096] f32

    // workspace: Wb (bf16, 8 MB) | Xb (bf16, 16 MB)
    unsigned short* Wb = (unsigned short*)d_ws;
    unsigned short* Xb = (unsigned short*)((char*)d_ws + (size_t)OUT_F * IN_F * 2);

    // fused prep: 1024 build_w blocks + 4096 cvt blocks
    prep_kernel<<<1024 + 4096, 256, 0, stream>>>(weight, alphas, x, Wb, (uint4*)Xb);

    const int grid = (M_DIM / GTM) * (N_DIM / GTN);   // 32*32 = 1024 blocks
    gemm_bt_kernel<<<grid, 256, 0, stream>>>((const bf16*)Xb, (const bf16*)Wb, bias, out);
}

// Round 7
// 226.941 us; speedup vs baseline: 1.7140x; 1.6672x over previous
//
#include <hip/hip_runtime.h>

typedef __bf16 bf16;
typedef __bf16 bf16x8 __attribute__((ext_vector_type(8)));
typedef float floatx4 __attribute__((ext_vector_type(4)));

#define IN_F  1024
#define OUT_F 4096
#define M_DIM 8192   // 16*512
#define K_DIM 1024
#define N_DIM 4096

__device__ __forceinline__ unsigned short f2bf(float f) {
    unsigned int u = __float_as_uint(f);
    u += 0x7FFFu + ((u >> 16) & 1u);   // round-to-nearest-even
    return (unsigned short)(u >> 16);
}

// ---------------------------------------------------------------------------
// Kernel 1 (FUSED prep): blocks [0,1024) build W' (factored diagonal sums),
// blocks [1024,5120) convert x f32->bf16.
// ---------------------------------------------------------------------------
__global__ __launch_bounds__(256) void prep_kernel(
    const float* __restrict__ W, const float* __restrict__ alphas,
    const float* __restrict__ x,
    unsigned short* __restrict__ Wb, uint4* __restrict__ xb)
{
    const int t = threadIdx.x;

    if (blockIdx.x >= 1024) {
        // ---- cvt_x part: 8 f32 -> 8 bf16 per thread ----
        const int g = (blockIdx.x - 1024) * 256 + t;
        const float4* xv = (const float4*)x;
        const float4 v0 = xv[2 * g];
        const float4 v1 = xv[2 * g + 1];
        uint4 o;
        o.x = (unsigned)f2bf(v0.x) | ((unsigned)f2bf(v0.y) << 16);
        o.y = (unsigned)f2bf(v0.z) | ((unsigned)f2bf(v0.w) << 16);
        o.z = (unsigned)f2bf(v1.x) | ((unsigned)f2bf(v1.y) << 16);
        o.w = (unsigned)f2bf(v1.z) | ((unsigned)f2bf(v1.w) << 16);
        xb[g] = o;
        return;
    }

    // ---- build_w part ----
    __shared__ __align__(16) float Wl[16 * 256];   // 16 KB source strip
    __shared__ __align__(16) float D2[2048];       // 8 KB
    __shared__ float D4[1024];                     // 4 KB
    __shared__ float D8[512];                      // 2 KB
    __shared__ float D16[256];                     // 1 KB

    const int rb = blockIdx.x >> 2;      // 256 row-blocks of 16 rows
    const int cb = blockIdx.x & 3;       // 4 col-blocks of 256 cols
    const int row0 = rb * 16, col0 = cb * 256;

    // pass 1: load strip (float4, coalesced)
    const float4* src = (const float4*)(W + (size_t)row0 * IN_F + col0);
    #pragma unroll
    for (int j = 0; j < 4; ++j) {
        const int idx = j * 256 + t;
        const int r = idx >> 6, c4 = idx & 63;
        ((float4*)Wl)[r * 64 + c4] = src[(size_t)r * 256 + c4];
    }

    // softmax over 5 alphas; fold in 1/bs
    float av[5];
    float mx = -1e30f;
    #pragma unroll
    for (int j = 0; j < 5; ++j) { av[j] = alphas[j]; mx = fmaxf(mx, av[j]); }
    float s = 0.f;
    #pragma unroll
    for (int j = 0; j < 5; ++j) { av[j] = __expf(av[j] - mx); s += av[j]; }
    const float inv = 1.f / s;
    #pragma unroll
    for (int j = 0; j < 5; ++j) av[j] *= inv;
    #pragma unroll
    for (int e = 1; e <= 4; ++e) av[e] *= 1.0f / (float)(1 << e);

    __syncthreads();

    // pass 2: per-(block,level,diagonal) sums, each computed once
    {   const int c16 = t >> 4, d = t & 15;
        float acc = 0.f;
        #pragma unroll
        for (int r = 0; r < 16; ++r)
            acc += Wl[r * 256 + c16 * 16 + ((r + d) & 15)];
        D16[t] = acc;
    }
    #pragma unroll
    for (int it = 0; it < 2; ++it) {
        const int s8 = t + it * 256;
        const int d = s8 & 7, c8 = (s8 >> 3) & 31, r8 = s8 >> 8;
        float acc = 0.f;
        #pragma unroll
        for (int r = 0; r < 8; ++r)
            acc += Wl[(r8 * 8 + r) * 256 + c8 * 8 + ((r + d) & 7)];
        D8[s8] = acc;
    }
    #pragma unroll
    for (int it = 0; it < 4; ++it) {
        const int s4 = t + it * 256;
        const int d = s4 & 3, c4 = (s4 >> 2) & 63, r4 = s4 >> 8;
        float acc = 0.f;
        #pragma unroll
        for (int r = 0; r < 4; ++r)
            acc += Wl[(r4 * 4 + r) * 256 + c4 * 4 + ((r + d) & 3)];
        D4[s4] = acc;
    }
    #pragma unroll
    for (int it = 0; it < 8; ++it) {
        const int s2 = t + it * 256;
        const int d = s2 & 1, c2 = (s2 >> 1) & 127, r2 = s2 >> 8;
        D2[s2] = Wl[(r2 * 2) * 256 + c2 * 2 + d]
               + Wl[(r2 * 2 + 1) * 256 + c2 * 2 + ((1 + d) & 1)];
    }

    __syncthreads();

    // pass 3: 16 outputs/thread, 5 LDS lookups each
    const int k = t >> 4, jj = t & 15;
    float res[16];
    #pragma unroll
    for (int jb = 0; jb < 16; ++jb) {
        const int col = jb * 16 + jj;
        const int dd = k - col;
        res[jb] = av[0] * Wl[k * 256 + col]
                + av[1] * D2[((k >> 1) * 128 + (col >> 1)) * 2 + (dd & 1)]
                + av[2] * D4[((k >> 2) * 64  + (col >> 2)) * 4 + (dd & 3)]
                + av[3] * D8[((k >> 3) * 32  + (col >> 3)) * 8 + (dd & 7)]
                + av[4] * D16[(col >> 4) * 16 + (dd & 15)];
    }

    // repack through LDS (reuse D2 region) for uint4 stores
    __syncthreads();
    unsigned short* st = (unsigned short*)D2;
    #pragma unroll
    for (int jb = 0; jb < 16; ++jb)
        st[k * 256 + jb * 16 + jj] = f2bf(res[jb]);
    __syncthreads();

    const uint4* p = (const uint4*)(st + k * 256 + jj * 16);
    uint4* dst = (uint4*)(Wb + (size_t)(row0 + k) * IN_F + col0 + jj * 16);
    dst[0] = p[0];
    dst[1] = p[1];
}

// ---------------------------------------------------------------------------
// Kernel 2 (v6 = v4 with the REGISTER BUDGET FIXED): C = A*B^T + bias
// Round-4/6 diagnosis: __launch_bounds__(256,3) caps the unified VGPR+AGPR
// budget at ~170/thread; acc[8][4]=128 + af/bfr=48 + addressing ~25 needs
// ~200 -> the compiler SPILLED ACCUMULATORS TO SCRATCH. Every spilled acc is
// re-loaded + re-stored per K-iteration: that was the 320 MB of "extra" HBM
// writes (scratch thrash through L2), MfmaUtil 10%, VGPR_Count 84.
// Fix: __launch_bounds__(256, 2) -> 256-reg budget, no spill, still
// 2 blocks/CU (8 waves) for cross-block epilogue/K-loop overlap.
// C stores reverted to normal (spill explains round-4's write amplification;
// round 3 at this store pattern measured clean 131 MB writes).
//   TM=256 x TN=128, BK=32, 256 thr = 4 waves (2M x 2N), acc[8][4]/wave.
//   dbuf 48 KB; counted vmcnt(6) (stage issued BEFORE wait, never a mid-loop
//   drain); setprio(1) around MFMA cluster.
// Swizzle (0-conflict, verified): chunk s of row r holds K-quad s^((r>>1)&3);
// frag read uses quad^((l16>>1)&3); staging pre-swizzles the GLOBAL source.
// ---------------------------------------------------------------------------
#define GTM 256
#define GTN 128
#define GTK 32
#define A_EL (GTM * GTK)          // 8192 el = 16 KB
#define B_EL (GTN * GTK)          // 4096 el =  8 KB
#define BUF_EL (A_EL + B_EL)      // 24 KB per slot

__global__ __launch_bounds__(256, 2) void gemm_bt_kernel(
    const bf16* __restrict__ A, const bf16* __restrict__ B,
    const float* __restrict__ bias, float* __restrict__ C)
{
    constexpr int N = N_DIM, K = K_DIM;
    constexpr int NT = K / GTK;            // 32 K-tiles

    __shared__ __align__(16) bf16 smem[2 * BUF_EL];   // 48 KB

    const int t    = threadIdx.x;
    const int w    = t >> 6;               // wave 0..3
    const int l    = t & 63;
    const int quad = l >> 4;
    const int l16  = l & 15;

    const int wm = (w >> 1) * 128;         // 0,128
    const int wn = (w & 1) * 64;           // 0,64

    const int nb = N / GTN;                // 32
    const int bm = blockIdx.x / nb;
    const int bn = blockIdx.x % nb;
    // natural order: per XCD bn in {x, x+8, x+16, x+24} -> B-panels resident
    // in its private L2 across all bm (round-1 lesson).

    // fragment read offset within a [rows][32] buffer (elements)
    const int fko = l16 * GTK + ((quad ^ ((l16 >> 1) & 3)) * 8);

    // staging: chunk c (16B) -> row = c>>2, K-quad = (c&3) ^ ((row>>1)&3)
    const bf16* Ag[4]; int la[4];
    const bf16* Bg[2]; int lb[2];
    {
        const bf16* Abase = A + (size_t)bm * GTM * K;
        const bf16* Bbase = B + (size_t)bn * GTN * K;
        #pragma unroll
        for (int q = 0; q < 4; ++q) {
            const int c = q * 256 + t;
            const int row = c >> 2;
            const int kq = (c & 3) ^ ((row >> 1) & 3);
            Ag[q] = Abase + (size_t)row * K + kq * 8;
            la[q] = (q * 256 + (t & ~63)) * 8;
        }
        #pragma unroll
        for (int q = 0; q < 2; ++q) {
            const int c = q * 256 + t;
            const int row = c >> 2;
            const int kq = (c & 3) ^ ((row >> 1) & 3);
            Bg[q] = Bbase + (size_t)row * K + kq * 8;
            lb[q] = (q * 256 + (t & ~63)) * 8;
        }
    }

    floatx4 acc[8][4] = {};

#define GLL(SRC, DST)                                                         \
    __builtin_amdgcn_global_load_lds(                                         \
        (const __attribute__((address_space(1))) void*)(SRC),                 \
        (__attribute__((address_space(3))) void*)(DST), 16, 0, 0)

#define STAGE(KOFF, BUFP) do {                                                \
        _Pragma("unroll")                                                     \
        for (int q = 0; q < 4; ++q) GLL(Ag[q] + (KOFF), (BUFP) + la[q]);      \
        _Pragma("unroll")                                                     \
        for (int q = 0; q < 2; ++q) GLL(Bg[q] + (KOFF), (BUFP) + A_EL + lb[q]); \
    } while (0)

#define MF(d, va, vb)                                                         \
    d = __builtin_amdgcn_mfma_f32_16x16x32_bf16(va, vb, d, 0, 0, 0)

    // prologue: stage tile 0 -> buf0
    STAGE(0, smem);

    #pragma unroll 1
    for (int kt = 0; kt < NT; ++kt) {
        bf16* cur = smem + (kt & 1) * BUF_EL;
        bf16* nxt = smem + ((kt & 1) ^ 1) * BUF_EL;

        if (kt < NT - 1) {
            STAGE((kt + 1) * GTK, nxt);                      // issue first
            asm volatile("s_waitcnt vmcnt(6)" ::: "memory"); // retire stage(kt)
        } else {
            asm volatile("s_waitcnt vmcnt(0)" ::: "memory"); // tail drain
        }
        __builtin_amdgcn_s_barrier();

        bf16x8 af[8], bfr[4];
        const bf16* a0 = cur + wm * GTK + fko;
        const bf16* b0 = cur + A_EL + wn * GTK + fko;
        #pragma unroll
        for (int n = 0; n < 4; ++n)
            bfr[n] = *(const bf16x8*)(b0 + n * 16 * GTK);
        #pragma unroll
        for (int m = 0; m < 8; ++m)
            af[m] = *(const bf16x8*)(a0 + m * 16 * GTK);

        __builtin_amdgcn_s_setprio(1);
        #pragma unroll
        for (int m = 0; m < 8; ++m)
            #pragma unroll
            for (int n = 0; n < 4; ++n)
                MF(acc[m][n], af[m], bfr[n]);
        __builtin_amdgcn_s_setprio(0);

        __builtin_amdgcn_s_barrier();   // reads(cur) done before next STAGE hits it
    }
#undef STAGE
#undef GLL
#undef MF

    // epilogue: C/D layout col = lane&15, row = quad*4 + reg (m89-verified)
    float bv[4];
    #pragma unroll
    for (int nt = 0; nt < 4; ++nt)
        bv[nt] = bias[bn * GTN + wn + nt * 16 + l16];

    float* Cbase = C + (size_t)(bm * GTM + wm) * N + bn * GTN + wn;
    #pragma unroll
    for (int m = 0; m < 8; ++m) {
        #pragma unroll
        for (int r = 0; r < 4; ++r) {
            float* crowp = Cbase + (size_t)(m * 16 + quad * 4 + r) * N;
            #pragma unroll
            for (int nt = 0; nt < 4; ++nt)
                crowp[nt * 16 + l16] = acc[m][nt][r] + bv[nt];
        }
    }
}

// ---------------------------------------------------------------------------
extern "C" void kernel_launch(void* const* d_in, const int* in_sizes, int n_in,
                              void* d_out, int out_size, void* d_ws, size_t ws_size,
                              hipStream_t stream) {
    const float* x      = (const float*)d_in[0];   // [16,512,1024]
    const float* weight = (const float*)d_in[1];   // [4096,1024]
    const float* alphas = (const float*)d_in[2];   // [5]
    const float* bias   = (const float*)d_in[3];   // [4096]
    float* out = (float*)d_out;                    // [16,512,4096] f32

    // workspace: Wb (bf16, 8 MB) | Xb (bf16, 16 MB)
    unsigned short* Wb = (unsigned short*)d_ws;
    unsigned short* Xb = (unsigned short*)((char*)d_ws + (size_t)OUT_F * IN_F * 2);

    // fused prep: 1024 build_w blocks + 4096 cvt blocks
    prep_kernel<<<1024 + 4096, 256, 0, stream>>>(weight, alphas, x, Wb, (uint4*)Xb);

    const int grid = (M_DIM / GTM) * (N_DIM / GTN);   // 32*32 = 1024 blocks
    gemm_bt_kernel<<<grid, 256, 0, stream>>>((const bf16*)Xb, (const bf16*)Wb, bias, out);
}

// Round 8
// 223.971 us; speedup vs baseline: 1.7367x; 1.0133x over previous
//
#include <hip/hip_runtime.h>

typedef __bf16 bf16;
typedef __bf16 bf16x8 __attribute__((ext_vector_type(8)));
typedef float floatx4 __attribute__((ext_vector_type(4)));

#define IN_F  1024
#define OUT_F 4096
#define M_DIM 8192   // 16*512
#define K_DIM 1024
#define N_DIM 4096

__device__ __forceinline__ unsigned short f2bf(float f) {
    unsigned int u = __float_as_uint(f);
    u += 0x7FFFu + ((u >> 16) & 1u);   // round-to-nearest-even
    return (unsigned short)(u >> 16);
}

// ---------------------------------------------------------------------------
// Kernel 1 (FUSED prep): blocks [0,1024) build W' (factored diagonal sums),
// blocks [1024,5120) convert x f32->bf16. (unchanged)
// ---------------------------------------------------------------------------
__global__ __launch_bounds__(256) void prep_kernel(
    const float* __restrict__ W, const float* __restrict__ alphas,
    const float* __restrict__ x,
    unsigned short* __restrict__ Wb, uint4* __restrict__ xb)
{
    const int t = threadIdx.x;

    if (blockIdx.x >= 1024) {
        const int g = (blockIdx.x - 1024) * 256 + t;
        const float4* xv = (const float4*)x;
        const float4 v0 = xv[2 * g];
        const float4 v1 = xv[2 * g + 1];
        uint4 o;
        o.x = (unsigned)f2bf(v0.x) | ((unsigned)f2bf(v0.y) << 16);
        o.y = (unsigned)f2bf(v0.z) | ((unsigned)f2bf(v0.w) << 16);
        o.z = (unsigned)f2bf(v1.x) | ((unsigned)f2bf(v1.y) << 16);
        o.w = (unsigned)f2bf(v1.z) | ((unsigned)f2bf(v1.w) << 16);
        xb[g] = o;
        return;
    }

    __shared__ __align__(16) float Wl[16 * 256];
    __shared__ __align__(16) float D2[2048];
    __shared__ float D4[1024];
    __shared__ float D8[512];
    __shared__ float D16[256];

    const int rb = blockIdx.x >> 2;
    const int cb = blockIdx.x & 3;
    const int row0 = rb * 16, col0 = cb * 256;

    const float4* src = (const float4*)(W + (size_t)row0 * IN_F + col0);
    #pragma unroll
    for (int j = 0; j < 4; ++j) {
        const int idx = j * 256 + t;
        const int r = idx >> 6, c4 = idx & 63;
        ((float4*)Wl)[r * 64 + c4] = src[(size_t)r * 256 + c4];
    }

    float av[5];
    float mx = -1e30f;
    #pragma unroll
    for (int j = 0; j < 5; ++j) { av[j] = alphas[j]; mx = fmaxf(mx, av[j]); }
    float s = 0.f;
    #pragma unroll
    for (int j = 0; j < 5; ++j) { av[j] = __expf(av[j] - mx); s += av[j]; }
    const float inv = 1.f / s;
    #pragma unroll
    for (int j = 0; j < 5; ++j) av[j] *= inv;
    #pragma unroll
    for (int e = 1; e <= 4; ++e) av[e] *= 1.0f / (float)(1 << e);

    __syncthreads();

    {   const int c16 = t >> 4, d = t & 15;
        float acc = 0.f;
        #pragma unroll
        for (int r = 0; r < 16; ++r)
            acc += Wl[r * 256 + c16 * 16 + ((r + d) & 15)];
        D16[t] = acc;
    }
    #pragma unroll
    for (int it = 0; it < 2; ++it) {
        const int s8 = t + it * 256;
        const int d = s8 & 7, c8 = (s8 >> 3) & 31, r8 = s8 >> 8;
        float acc = 0.f;
        #pragma unroll
        for (int r = 0; r < 8; ++r)
            acc += Wl[(r8 * 8 + r) * 256 + c8 * 8 + ((r + d) & 7)];
        D8[s8] = acc;
    }
    #pragma unroll
    for (int it = 0; it < 4; ++it) {
        const int s4 = t + it * 256;
        const int d = s4 & 3, c4 = (s4 >> 2) & 63, r4 = s4 >> 8;
        float acc = 0.f;
        #pragma unroll
        for (int r = 0; r < 4; ++r)
            acc += Wl[(r4 * 4 + r) * 256 + c4 * 4 + ((r + d) & 3)];
        D4[s4] = acc;
    }
    #pragma unroll
    for (int it = 0; it < 8; ++it) {
        const int s2 = t + it * 256;
        const int d = s2 & 1, c2 = (s2 >> 1) & 127, r2 = s2 >> 8;
        D2[s2] = Wl[(r2 * 2) * 256 + c2 * 2 + d]
               + Wl[(r2 * 2 + 1) * 256 + c2 * 2 + ((1 + d) & 1)];
    }

    __syncthreads();

    const int k = t >> 4, jj = t & 15;
    float res[16];
    #pragma unroll
    for (int jb = 0; jb < 16; ++jb) {
        const int col = jb * 16 + jj;
        const int dd = k - col;
        res[jb] = av[0] * Wl[k * 256 + col]
                + av[1] * D2[((k >> 1) * 128 + (col >> 1)) * 2 + (dd & 1)]
                + av[2] * D4[((k >> 2) * 64  + (col >> 2)) * 4 + (dd & 3)]
                + av[3] * D8[((k >> 3) * 32  + (col >> 3)) * 8 + (dd & 7)]
                + av[4] * D16[(col >> 4) * 16 + (dd & 15)];
    }

    __syncthreads();
    unsigned short* st = (unsigned short*)D2;
    #pragma unroll
    for (int jb = 0; jb < 16; ++jb)
        st[k * 256 + jb * 16 + jj] = f2bf(res[jb]);
    __syncthreads();

    const uint4* p = (const uint4*)(st + k * 256 + jj * 16);
    uint4* dst = (uint4*)(Wb + (size_t)(row0 + k) * IN_F + col0 + jj * 16);
    dst[0] = p[0];
    dst[1] = p[1];
}

// ---------------------------------------------------------------------------
// Kernel 2 (v7): faithful m201-style 8-phase 256x256 MFMA GEMM.
//   BK=64, 512 thr = 8 waves (2M x 4N), per-wave 128x64, acc[8][4].
//   LDS 128 KiB = 2 dbuf x [A-h0|A-h1|B-h0|B-h1], half = 128 rows x 64 K.
//   4 phases/K-tile x 16 MFMA: quadrants (m0-3/m4-7 x n0-1/n2-3), A/B frag
//   register reuse -> 24 ds_read_b128 per 64 MFMA.
//   Each phase: {ds_reads || 1 half stage -> BAR -> lgkm0+sched_barrier ->
//   setprio(1) 16 MFMA setprio(0) -> BAR}.
//   Stage schedule (region-safe): Ph1/2 stage T+1's A into OTHER slot;
//   Ph3/4 stage T+2's B into CURRENT slot (B-region free after Ph2 barrier,
//   A-region after Ph3). Boundary queue = 8 loads -> constant vmcnt(4);
//   drain only at tiles 14/15 (tail).
//   Swizzle: chunk c of row r holds K-chunk c^(r&7) (8x16B chunks/row);
//   frag read chunk = (ks*4+quad)^(l16&7) -> 2 lanes/bank (free).
//   Reg ledger: acc 128 (AGPR) + af 32 + bfr 32 + ~30 addr ~= 222 <= 256
//   at __launch_bounds__(512,2) -> no spill (round-6 lesson: verify first).
// ---------------------------------------------------------------------------
#define BK2 64
#define HEL 8192            // half-tile elements (128 rows x 64 K)
#define SEL (4 * HEL)       // slot elements (64 KB)

__global__ __launch_bounds__(512, 2) void gemm_bt_kernel(
    const bf16* __restrict__ A, const bf16* __restrict__ B,
    const float* __restrict__ bias, float* __restrict__ C)
{
    constexpr int N = N_DIM, K = K_DIM;

    __shared__ __align__(16) bf16 smem[2 * SEL];   // 131072 B

    const int t    = threadIdx.x;
    const int w    = t >> 6;
    const int l    = t & 63;
    const int quad = l >> 4;
    const int l16  = l & 15;

    const int wr = w >> 2;           // 0..1 -> A half
    const int wc = w & 3;            // 0..3 -> B half = wc>>1
    const int wm = wr * 128;
    const int wn = wc * 64;

    const int bm = blockIdx.x >> 4;  // 32 (natural order: B-panels L2-resident)
    const int bn = blockIdx.x & 15;  // 16

    // fragment read offsets (elements, within a half)
    const int fk0 = ((0 * 4 + quad) ^ (l16 & 7)) * 8;
    const int fk1 = ((1 * 4 + quad) ^ (l16 & 7)) * 8;
    const int arow = wr * HEL + l16 * 64;                           // + m*1024
    const int brow = (2 + (wc >> 1)) * HEL + ((wc & 1) * 64 + l16) * 64; // + n*1024

    // staging: thread t handles chunks {t, t+512} of each half.
    // chunk c: row = c>>3, lds-chunk = c&7 holds K-chunk (c&7)^(row&7).
    const int r0  = t >> 3;                       // 0..63 (chunk2 = row+64)
    const int kc0 = ((t & 7) ^ (r0 & 7)) * 8;
    const bf16* pA = A + (size_t)(bm * 256 + r0) * K + kc0;
    const bf16* pB = B + (size_t)(bn * 256 + r0) * K + kc0;
    const int t8 = t * 8;                         // lane-linear LDS dest

    floatx4 acc[8][4] = {};
    bf16x8 af[4][2], bfr[4][2];

#define GLL(SRC, DSTOFF)                                                      \
    __builtin_amdgcn_global_load_lds(                                         \
        (const __attribute__((address_space(1))) void*)(SRC),                 \
        (__attribute__((address_space(3))) void*)(smem + (DSTOFF)), 16, 0, 0)

#define STAGE_A(H, TT, SL) do {                                               \
    GLL(pA + (size_t)(H) * 128 * K + (TT) * BK2,          (SL) + (H) * HEL + t8);        \
    GLL(pA + (size_t)(H) * 128 * K + 64 * K + (TT) * BK2, (SL) + (H) * HEL + 4096 + t8); \
} while (0)
#define STAGE_B(H, TT, SL) do {                                               \
    GLL(pB + (size_t)(H) * 128 * K + (TT) * BK2,          (SL) + (2 + (H)) * HEL + t8);        \
    GLL(pB + (size_t)(H) * 128 * K + 64 * K + (TT) * BK2, (SL) + (2 + (H)) * HEL + 4096 + t8); \
} while (0)

#define RD_A(MB, SC) do { _Pragma("unroll")                                   \
    for (int mi = 0; mi < 4; ++mi) {                                          \
        af[mi][0] = *(const bf16x8*)(smem + (SC) + arow + ((MB) + mi) * 1024 + fk0); \
        af[mi][1] = *(const bf16x8*)(smem + (SC) + arow + ((MB) + mi) * 1024 + fk1); \
    } } while (0)
#define RD_B(NB, SC) do { _Pragma("unroll")                                   \
    for (int ni = 0; ni < 2; ++ni) {                                          \
        bfr[(NB) + ni][0] = *(const bf16x8*)(smem + (SC) + brow + ((NB) + ni) * 1024 + fk0); \
        bfr[(NB) + ni][1] = *(const bf16x8*)(smem + (SC) + brow + ((NB) + ni) * 1024 + fk1); \
    } } while (0)

#define MFMA16(MB, NB) do {                                                   \
    __builtin_amdgcn_s_setprio(1);                                            \
    _Pragma("unroll")                                                         \
    for (int mi = 0; mi < 4; ++mi)                                            \
        _Pragma("unroll")                                                     \
        for (int ni = 0; ni < 2; ++ni) {                                      \
            acc[(MB)+mi][(NB)+ni] = __builtin_amdgcn_mfma_f32_16x16x32_bf16(  \
                af[mi][0], bfr[(NB)+ni][0], acc[(MB)+mi][(NB)+ni], 0, 0, 0);  \
            acc[(MB)+mi][(NB)+ni] = __builtin_amdgcn_mfma_f32_16x16x32_bf16(  \
                af[mi][1], bfr[(NB)+ni][1], acc[(MB)+mi][(NB)+ni], 0, 0, 0);  \
        }                                                                     \
    __builtin_amdgcn_s_setprio(0);                                            \
} while (0)

#define BAR() __builtin_amdgcn_s_barrier()
#define LGKM0() do { asm volatile("s_waitcnt lgkmcnt(0)" ::: "memory");       \
                     __builtin_amdgcn_sched_barrier(0); } while (0)

    // one K-tile = 4 phases; TRAIL = boundary vmcnt wait (before final BAR)
#define TILE(TT, SC, SO, DOA, DOB, TRAIL) do {                                \
    /* Ph1: A m0-3 (8 rd) + B n0-1 (4 rd); stage T+1.A-h0 -> SO */            \
    RD_A(0, SC); RD_B(0, SC); if (DOA) STAGE_A(0, (TT) + 1, SO);              \
    BAR(); LGKM0(); MFMA16(0, 0); BAR();                                      \
    /* Ph2: B n2-3 (4 rd); stage T+1.A-h1 -> SO */                            \
    RD_B(2, SC); if (DOA) STAGE_A(1, (TT) + 1, SO);                           \
    BAR(); LGKM0(); MFMA16(0, 2); BAR();                                      \
    /* Ph3: A m4-7 (8 rd); stage T+2.B-h0 -> SC (B-region free since Ph2) */  \
    RD_A(4, SC); if (DOB) STAGE_B(0, (TT) + 2, SC);                           \
    BAR(); LGKM0(); MFMA16(4, 0); BAR();                                      \
    /* Ph4: no reads; stage T+2.B-h1 -> SC */                                 \
    if (DOB) STAGE_B(1, (TT) + 2, SC);                                        \
    BAR(); MFMA16(4, 2);                                                      \
    TRAIL; BAR();                                                             \
} while (0)

    // ---- prologue (queue order matches steady state): T0.B, T0.A, T1.B ----
    STAGE_B(0, 0, 0);   STAGE_B(1, 0, 0);
    STAGE_A(0, 0, 0);   STAGE_A(1, 0, 0);
    STAGE_B(0, 1, SEL); STAGE_B(1, 1, SEL);
    asm volatile("s_waitcnt vmcnt(4)" ::: "memory");   // retire T0 (8), keep T1.B (4)
    BAR();

    // ---- main loop: tiles 0..11 (all guards true, constant vmcnt(4)) ----
    #pragma unroll 1
    for (int T = 0; T < 12; T += 2) {
        TILE(T,     0,   SEL, true, true, asm volatile("s_waitcnt vmcnt(4)" ::: "memory"));
        TILE(T + 1, SEL, 0,   true, true, asm volatile("s_waitcnt vmcnt(4)" ::: "memory"));
    }
    // ---- peeled tail: tiles 12..15 ----
    TILE(12, 0,   SEL, true,  true,  asm volatile("s_waitcnt vmcnt(4)" ::: "memory"));
    TILE(13, SEL, 0,   true,  true,  asm volatile("s_waitcnt vmcnt(4)" ::: "memory"));
    TILE(14, 0,   SEL, true,  false, asm volatile("s_waitcnt vmcnt(0)" ::: "memory"));
    TILE(15, SEL, 0,   false, false, (void)0);

#undef TILE
#undef LGKM0
#undef BAR
#undef MFMA16
#undef RD_B
#undef RD_A
#undef STAGE_B
#undef STAGE_A
#undef GLL

    // ---- epilogue: C/D layout col = lane&15, row = quad*4 + reg ----
    float bv[4];
    #pragma unroll
    for (int nt = 0; nt < 4; ++nt)
        bv[nt] = bias[bn * 256 + wn + nt * 16 + l16];

    float* Cbase = C + (size_t)(bm * 256 + wm) * N + bn * 256 + wn;
    #pragma unroll
    for (int m = 0; m < 8; ++m) {
        #pragma unroll
        for (int r = 0; r < 4; ++r) {
            float* crowp = Cbase + (size_t)(m * 16 + quad * 4 + r) * N;
            #pragma unroll
            for (int nt = 0; nt < 4; ++nt)
                crowp[nt * 16 + l16] = acc[m][nt][r] + bv[nt];
        }
    }
}

// ---------------------------------------------------------------------------
extern "C" void kernel_launch(void* const* d_in, const int* in_sizes, int n_in,
                              void* d_out, int out_size, void* d_ws, size_t ws_size,
                              hipStream_t stream) {
    const float* x      = (const float*)d_in[0];   // [16,512,1024]
    const float* weight = (const float*)d_in[1];   // [4096,1024]
    const float* alphas = (const float*)d_in[2];   // [5]
    const float* bias   = (const float*)d_in[3];   // [4096]
    float* out = (float*)d_out;                    // [16,512,4096] f32

    // workspace: Wb (bf16, 8 MB) | Xb (bf16, 16 MB)
    unsigned short* Wb = (unsigned short*)d_ws;
    unsigned short* Xb = (unsigned short*)((char*)d_ws + (size_t)OUT_F * IN_F * 2);

    prep_kernel<<<1024 + 4096, 256, 0, stream>>>(weight, alphas, x, Wb, (uint4*)Xb);

    const int grid = (M_DIM / 256) * (N_DIM / 256);   // 32*16 = 512 blocks
    gemm_bt_kernel<<<grid, 512, 0, stream>>>((const bf16*)Xb, (const bf16*)Wb, bias, out);
}